// Round 2
// baseline (116.035 us; speedup 1.0000x reference)
//
#include <hip/hip_runtime.h>
#include <hip/hip_bf16.h>

// Problem constants (match setup_inputs: B=2, N=768, H=W=160)
#define BATCH   2
#define NG      768
#define H_      160
#define W_      160
#define NPIX    (H_ * W_)          // 25600
#define NCHUNK  8
#define CHUNK   (NG / NCHUNK)      // 96
#define EPS2D_  0.3f
#define SZ2_    1.0e-6f            // 0.001^2
#define ALPHA_MAX_ 0.999f
#define KEXP    (-0.7213475204444817f)   // -0.5 * log2(e)

// Per-gaussian polynomial form:
//   alpha = min( exp2( A x^2 + B xy + C y^2 + D x + E y + F ), 0.999 )
// with log2(opacity) folded into F.
struct __align__(16) GP {
    float A, B, C, D;
    float E, F, cr, cg;
    float cb, pad0, pad1, pad2;
};

__global__ __launch_bounds__(256)
void gr_precompute(const float* __restrict__ means,
                   const float* __restrict__ scales,
                   const float* __restrict__ rots,
                   const float* __restrict__ colors,
                   const float* __restrict__ opac,
                   GP* __restrict__ gp, int total) {
    int i = blockIdx.x * blockDim.x + threadIdx.x;
    if (i >= total) return;
    float theta = rots[i];
    float c = cosf(theta), s = sinf(theta);
    float sx = scales[2*i], sy = scales[2*i+1];
    float sx2 = sx*sx, sy2 = sy*sy;
    float a  = c*c*sx2 + s*s*sy2;
    float bb = c*s*(sx2 - sy2);
    float d  = s*s*sx2 + c*c*sy2;
    float mx = means[2*i], my = means[2*i+1];
    float cxx = a + SZ2_*mx*mx + EPS2D_;
    float cxy = bb + SZ2_*mx*my;
    float cyy = d + SZ2_*my*my + EPS2D_;
    float det = cxx*cyy - cxy*cxy;
    float inv = 1.0f / det;
    float ca  =  cyy * inv;
    float cb2 = -cxy * inv;
    float cc  =  cxx * inv;
    GP g;
    g.A = KEXP * ca;
    g.B = KEXP * 2.0f * cb2;
    g.C = KEXP * cc;
    g.D = KEXP * (-2.0f * ca * mx - 2.0f * cb2 * my);
    g.E = KEXP * (-2.0f * cc * my - 2.0f * cb2 * mx);
    g.F = KEXP * (ca*mx*mx + 2.0f*cb2*mx*my + cc*my*my) + log2f(opac[i]);
    g.cr = colors[3*i]; g.cg = colors[3*i+1]; g.cb = colors[3*i+2];
    g.pad0 = 0.f; g.pad1 = 0.f; g.pad2 = 0.f;
    gp[i] = g;
}

// 512 threads = 8 waves. All waves share the same 64 pixels; wave w composites
// chunk w (96 gaussians). Partials combined through LDS; output written by wave 0.
__global__ __launch_bounds__(512)
void gr_render(const GP* __restrict__ gp, float* __restrict__ out) {
    __shared__ float4 lds[NCHUNK][64];
    int tid  = threadIdx.x;
    int wave = tid >> 6;
    int lane = tid & 63;
    int p = blockIdx.x * 64 + lane;        // [0, NPIX)
    int b = blockIdx.y;
    float px = (float)(p % W_) + 0.5f;
    float py = (float)(p / W_) + 0.5f;
    float x2 = px*px, xy = px*py, y2 = py*py;
    const GP* __restrict__ g = gp + b * NG + wave * CHUNK;

    float r = 0.f, gg = 0.f, bl = 0.f, T = 1.f;

    for (int t0 = 0; t0 < CHUNK; t0 += 8) {
        #pragma unroll
        for (int k = 0; k < 8; ++k) {
            GP gv = g[t0 + k];             // wave-uniform -> scalar loads
            float q = fmaf(gv.A, x2,
                      fmaf(gv.B, xy,
                      fmaf(gv.C, y2,
                      fmaf(gv.D, px,
                      fmaf(gv.E, py, gv.F)))));
            float al = fminf(__builtin_exp2f(q), ALPHA_MAX_);
            float w  = T * al;
            r  = fmaf(w, gv.cr, r);
            gg = fmaf(w, gv.cg, gg);
            bl = fmaf(w, gv.cb, bl);
            T -= w;
        }
        // chunk-local early exit: remaining contribution bounded by T < 1e-4
        if (__all(T < 1.0e-4f)) break;
    }

    lds[wave][lane] = make_float4(r, gg, bl, T);
    __syncthreads();

    if (wave == 0) {
        // res = o0 + T0*(o1 + T1*(... + T6*o7)), accumulated back-to-front
        float4 o = lds[NCHUNK-1][lane];
        float cr_ = o.x, cg_ = o.y, cb_ = o.z;
        #pragma unroll
        for (int i = NCHUNK-2; i >= 0; --i) {
            float4 oi = lds[i][lane];
            cr_ = fmaf(oi.w, cr_, oi.x);
            cg_ = fmaf(oi.w, cg_, oi.y);
            cb_ = fmaf(oi.w, cb_, oi.z);
        }
        cr_ = fminf(fmaxf(cr_, 0.f), 1.f);
        cg_ = fminf(fmaxf(cg_, 0.f), 1.f);
        cb_ = fminf(fmaxf(cb_, 0.f), 1.f);
        out[(b*3 + 0) * NPIX + p] = cr_;
        out[(b*3 + 1) * NPIX + p] = cg_;
        out[(b*3 + 2) * NPIX + p] = cb_;
    }
}

extern "C" void kernel_launch(void* const* d_in, const int* in_sizes, int n_in,
                              void* d_out, int out_size, void* d_ws, size_t ws_size,
                              hipStream_t stream) {
    const float* means  = (const float*)d_in[0];
    const float* scales = (const float*)d_in[1];
    const float* rots   = (const float*)d_in[2];
    const float* colors = (const float*)d_in[3];
    const float* opac   = (const float*)d_in[4];
    float* out = (float*)d_out;

    GP* gp = (GP*)d_ws;
    int total = BATCH * NG;
    gr_precompute<<<(total + 255) / 256, 256, 0, stream>>>(
        means, scales, rots, colors, opac, gp, total);

    dim3 rgrid(NPIX / 64, BATCH);          // (400, 2) blocks x 512 threads
    gr_render<<<rgrid, 512, 0, stream>>>(gp, out);
}

// Round 3
// 93.708 us; speedup vs baseline: 1.2383x; 1.2383x over previous
//
#include <hip/hip_runtime.h>
#include <hip/hip_bf16.h>

// Problem constants (match setup_inputs: B=2, N=768, H=W=160)
#define BATCH   2
#define NG      768
#define H_      160
#define W_      160
#define NPIX    (H_ * W_)          // 25600
#define NCHUNK  8
#define CHUNK   (NG / NCHUNK)      // 96
#define EPS2D_  0.3f
#define SZ2_    1.0e-6f            // 0.001^2
#define ALPHA_MAX_ 0.999f
#define KEXP    (-0.7213475204444817f)   // -0.5 * log2(e)

// Per-gaussian polynomial form:
//   alpha = min( exp2( A x^2 + B xy + C y^2 + D x + E y + F ), 0.999 )
// with log2(opacity) folded into F.
struct __align__(16) GP {
    float A, B, C, D;
    float E, F, cr, cg;
    float cb, pad0, pad1, pad2;
};

__global__ __launch_bounds__(256)
void gr_precompute(const float* __restrict__ means,
                   const float* __restrict__ scales,
                   const float* __restrict__ rots,
                   const float* __restrict__ colors,
                   const float* __restrict__ opac,
                   GP* __restrict__ gp, int total) {
    int i = blockIdx.x * blockDim.x + threadIdx.x;
    if (i >= total) return;
    float theta = rots[i];
    float c = cosf(theta), s = sinf(theta);
    float sx = scales[2*i], sy = scales[2*i+1];
    float sx2 = sx*sx, sy2 = sy*sy;
    float a  = c*c*sx2 + s*s*sy2;
    float bb = c*s*(sx2 - sy2);
    float d  = s*s*sx2 + c*c*sy2;
    float mx = means[2*i], my = means[2*i+1];
    float cxx = a + SZ2_*mx*mx + EPS2D_;
    float cxy = bb + SZ2_*mx*my;
    float cyy = d + SZ2_*my*my + EPS2D_;
    float det = cxx*cyy - cxy*cxy;
    float inv = 1.0f / det;
    float ca  =  cyy * inv;
    float cb2 = -cxy * inv;
    float cc  =  cxx * inv;
    GP g;
    g.A = KEXP * ca;
    g.B = KEXP * 2.0f * cb2;
    g.C = KEXP * cc;
    g.D = KEXP * (-2.0f * ca * mx - 2.0f * cb2 * my);
    g.E = KEXP * (-2.0f * cc * my - 2.0f * cb2 * mx);
    g.F = KEXP * (ca*mx*mx + 2.0f*cb2*mx*my + cc*my*my) + log2f(opac[i]);
    g.cr = colors[3*i]; g.cg = colors[3*i+1]; g.cb = colors[3*i+2];
    g.pad0 = 0.f; g.pad1 = 0.f; g.pad2 = 0.f;
    gp[i] = g;
}

// One thread per pixel; chunk index comes from blockIdx.y (PROVABLY uniform ->
// compiler scalarizes gaussian loads to s_load; SGPR~80/VGPR~12 in R1 evidence).
__global__ __launch_bounds__(256)
void gr_render(const GP* __restrict__ gp, float4* __restrict__ part) {
    int p     = blockIdx.x * 256 + threadIdx.x;   // [0, NPIX)
    int chunk = blockIdx.y;                        // uniform
    int b     = blockIdx.z;
    float px = (float)(p % W_) + 0.5f;
    float py = (float)(p / W_) + 0.5f;
    float x2 = px*px, xy = px*py, y2 = py*py;
    const GP* __restrict__ g = gp + b * NG + chunk * CHUNK;

    float r = 0.f, gg = 0.f, bl = 0.f, T = 1.f;

    for (int t0 = 0; t0 < CHUNK; t0 += 16) {
        #pragma unroll
        for (int k = 0; k < 16; ++k) {
            GP gv = g[t0 + k];                     // s_load expected
            float q = fmaf(gv.A, x2,
                      fmaf(gv.B, xy,
                      fmaf(gv.C, y2,
                      fmaf(gv.D, px,
                      fmaf(gv.E, py, gv.F)))));
            float al = fminf(__builtin_exp2f(q), ALPHA_MAX_);
            float w  = T * al;
            r  = fmaf(w, gv.cr, r);
            gg = fmaf(w, gv.cg, gg);
            bl = fmaf(w, gv.cb, bl);
            T -= w;
        }
        // chunk-local early exit: remaining contribution bounded by T < 1e-4
        if (__all(T < 1.0e-4f)) break;
    }
    part[(chunk * BATCH + b) * NPIX + p] = make_float4(r, gg, bl, T);
}

__global__ __launch_bounds__(256)
void gr_combine(const float4* __restrict__ part, float* __restrict__ out) {
    int idx = blockIdx.x * 256 + threadIdx.x;     // [0, BATCH*NPIX)
    if (idx >= BATCH * NPIX) return;
    int b = idx / NPIX;
    int p = idx - b * NPIX;
    // res = o0 + T0*(o1 + T1*(... + T6*o7)), accumulated back-to-front
    float4 o = part[((NCHUNK-1) * BATCH + b) * NPIX + p];
    float r = o.x, gg = o.y, bb = o.z;
    #pragma unroll
    for (int i = NCHUNK-2; i >= 0; --i) {
        float4 oi = part[(i * BATCH + b) * NPIX + p];
        r  = fmaf(oi.w, r,  oi.x);
        gg = fmaf(oi.w, gg, oi.y);
        bb = fmaf(oi.w, bb, oi.z);
    }
    r  = fminf(fmaxf(r , 0.f), 1.f);
    gg = fminf(fmaxf(gg, 0.f), 1.f);
    bb = fminf(fmaxf(bb, 0.f), 1.f);
    out[(b * 3 + 0) * NPIX + p] = r;
    out[(b * 3 + 1) * NPIX + p] = gg;
    out[(b * 3 + 2) * NPIX + p] = bb;
}

extern "C" void kernel_launch(void* const* d_in, const int* in_sizes, int n_in,
                              void* d_out, int out_size, void* d_ws, size_t ws_size,
                              hipStream_t stream) {
    const float* means  = (const float*)d_in[0];
    const float* scales = (const float*)d_in[1];
    const float* rots   = (const float*)d_in[2];
    const float* colors = (const float*)d_in[3];
    const float* opac   = (const float*)d_in[4];
    float* out = (float*)d_out;

    GP* gp = (GP*)d_ws;
    size_t gp_bytes = (size_t)BATCH * NG * sizeof(GP);
    gp_bytes = (gp_bytes + 255) & ~(size_t)255;
    float4* part = (float4*)((char*)d_ws + gp_bytes);

    int total = BATCH * NG;
    gr_precompute<<<(total + 255) / 256, 256, 0, stream>>>(
        means, scales, rots, colors, opac, gp, total);

    dim3 rgrid(NPIX / 256, NCHUNK, BATCH);   // (100, 8, 2)
    gr_render<<<rgrid, 256, 0, stream>>>(gp, part);

    gr_combine<<<(BATCH * NPIX + 255) / 256, 256, 0, stream>>>(part, out);
}

// Round 4
// 77.799 us; speedup vs baseline: 1.4915x; 1.2045x over previous
//
#include <hip/hip_runtime.h>
#include <hip/hip_fp16.h>
#include <string.h>

// Problem constants (match setup_inputs: B=2, N=768, H=W=160)
#define BATCH   2
#define NG      768
#define H_      160
#define W_      160
#define NPIX    (H_ * W_)          // 25600
#define NCHUNK  8
#define CHUNK   (NG / NCHUNK)      // 96
#define TILE    8
#define TPD     (W_ / TILE)        // 20 tiles per dim
#define NTILE   (TPD * TPD)        // 400
#define EPS2D_  0.3f
#define SZ2_    1.0e-6f            // 0.001^2
#define ALPHA_MAX_ 0.999f
#define KEXP    (-0.7213475204444817f)   // -0.5 * log2(e)
#define LN_CULL_EPS (-13.815511f)        // ln(1e-6): cull gaussians with max alpha < 1e-6

// cull[i]    = (mx, my, ex, ey)            : mean + axis-aligned influence extent
// pay[2i]    = (A, B, C, D)                : alpha = min(exp2(A x^2+B xy+C y^2+D x+E y+F), .999)
// pay[2i+1]  = (E, F, half2(cr,cg), cb)

__global__ __launch_bounds__(256)
void gr_precompute(const float* __restrict__ means,
                   const float* __restrict__ scales,
                   const float* __restrict__ rots,
                   const float* __restrict__ colors,
                   const float* __restrict__ opac,
                   float4* __restrict__ cull, float4* __restrict__ pay, int total) {
    int i = blockIdx.x * blockDim.x + threadIdx.x;
    if (i >= total) return;
    float theta = rots[i];
    float c = cosf(theta), s = sinf(theta);
    float sx = scales[2*i], sy = scales[2*i+1];
    float sx2 = sx*sx, sy2 = sy*sy;
    float a  = c*c*sx2 + s*s*sy2;
    float bb = c*s*(sx2 - sy2);
    float d  = s*s*sx2 + c*c*sy2;
    float mx = means[2*i], my = means[2*i+1];
    float cxx = a + SZ2_*mx*mx + EPS2D_;
    float cxy = bb + SZ2_*mx*my;
    float cyy = d + SZ2_*my*my + EPS2D_;
    float det = cxx*cyy - cxy*cxy;
    float inv = 1.0f / det;
    float ca  =  cyy * inv;
    float cb2 = -cxy * inv;
    float cc  =  cxx * inv;
    float op  = opac[i];

    // influence extent: alpha >= eps  =>  mahalanobis^2 <= 2*ln(op/eps)
    // marginal projection: |dx| <= k*sqrt(cov_xx), |dy| <= k*sqrt(cov_yy)
    float k2 = 2.0f * (logf(op) - LN_CULL_EPS);
    k2 = fmaxf(k2, 0.0f);
    float kk = sqrtf(k2);
    float ex = kk * sqrtf(cxx);
    float ey = kk * sqrtf(cyy);
    cull[i] = make_float4(mx, my, ex, ey);

    float A = KEXP * ca;
    float B = KEXP * 2.0f * cb2;
    float C = KEXP * cc;
    float D = KEXP * (-2.0f * ca * mx - 2.0f * cb2 * my);
    float E = KEXP * (-2.0f * cc * my - 2.0f * cb2 * mx);
    float F = KEXP * (ca*mx*mx + 2.0f*cb2*mx*my + cc*my*my) + log2f(op);
    float cr = colors[3*i], cg = colors[3*i+1], cb = colors[3*i+2];
    __half2 h2 = __floats2half2_rn(cr, cg);
    float rg; memcpy(&rg, &h2, 4);
    pay[2*i]   = make_float4(A, B, C, D);
    pay[2*i+1] = make_float4(E, F, rg, cb);
}

// Block = one 8x8 pixel tile x 4 waves; wave w handles chunk blockIdx.y*4+w.
// Per-wave: box-cull chunk against tile -> order-preserving compaction into
// this wave's LDS region -> composite survivors via broadcast ds_read.
// No inter-wave LDS sharing -> no __syncthreads needed.
__global__ __launch_bounds__(256)
void gr_render(const float4* __restrict__ cull, const float4* __restrict__ pay,
               float4* __restrict__ part) {
    __shared__ float4 lds[4][CHUNK * 2];
    int tid  = threadIdx.x;
    int wave = tid >> 6;
    int lane = tid & 63;
    int tile = blockIdx.x;                  // [0, 400)
    int chunk = blockIdx.y * 4 + wave;      // [0, 8)
    int b    = blockIdx.z;
    int tx = tile % TPD, ty = tile / TPD;
    int pxi = tx * TILE + (lane & 7);
    int pyi = ty * TILE + (lane >> 3);
    float px = (float)pxi + 0.5f;
    float py = (float)pyi + 0.5f;
    float cxm = (float)(tx * TILE) + 0.5f * TILE;   // tile center
    float cym = (float)(ty * TILE) + 0.5f * TILE;
    const float RH = 0.5f * TILE;                   // tile half-extent (4)

    int base = b * NG + chunk * CHUNK;
    int cnt = 0;

    // ---- cull + order-preserving compaction (chunk = 64 + 32 gaussians) ----
    {   // batch 0: gaussians [0, 64)
        float4 cu = cull[base + lane];
        bool keep = (fabsf(cu.x - cxm) <= cu.z + RH) &&
                    (fabsf(cu.y - cym) <= cu.w + RH);
        unsigned long long m = __ballot(keep);
        unsigned pre = __builtin_amdgcn_mbcnt_hi((unsigned)(m >> 32),
                        __builtin_amdgcn_mbcnt_lo((unsigned)m, 0u));
        if (keep) {
            int gi = base + lane;
            lds[wave][2*pre]     = pay[2*gi];
            lds[wave][2*pre + 1] = pay[2*gi + 1];
        }
        cnt = (int)__popcll(m);
    }
    {   // batch 1: gaussians [64, 96) — lanes 32..63 idle
        bool valid = lane < (CHUNK - 64);
        int gi = base + 64 + (valid ? lane : 0);    // clamped, always in-bounds
        float4 cu = cull[gi];
        bool keep = valid &&
                    (fabsf(cu.x - cxm) <= cu.z + RH) &&
                    (fabsf(cu.y - cym) <= cu.w + RH);
        unsigned long long m = __ballot(keep);
        unsigned pre = __builtin_amdgcn_mbcnt_hi((unsigned)(m >> 32),
                        __builtin_amdgcn_mbcnt_lo((unsigned)m, 0u));
        if (keep) {
            int slot = cnt + (int)pre;
            lds[wave][2*slot]     = pay[2*gi];
            lds[wave][2*slot + 1] = pay[2*gi + 1];
        }
        cnt += (int)__popcll(m);
    }

    // ---- composite survivors (broadcast ds_read, uniform address) ----
    float r = 0.f, g = 0.f, bl = 0.f, T = 1.f;
    float x2 = px*px, xy = px*py, y2 = py*py;
    for (int i = 0; i < cnt; ++i) {
        float4 av = lds[wave][2*i];
        float4 ev = lds[wave][2*i + 1];
        float q = fmaf(av.x, x2,
                  fmaf(av.y, xy,
                  fmaf(av.z, y2,
                  fmaf(av.w, px,
                  fmaf(ev.x, py, ev.y)))));
        float al = fminf(__builtin_exp2f(q), ALPHA_MAX_);
        float w  = T * al;
        __half2 h2; memcpy(&h2, &ev.z, 4);
        float2 rg = __half22float2(h2);
        r  = fmaf(w, rg.x, r);
        g  = fmaf(w, rg.y, g);
        bl = fmaf(w, ev.w, bl);
        T -= w;
        if (((i & 7) == 7) && __all(T < 1.0e-4f)) break;
    }
    part[(chunk * BATCH + b) * NPIX + pyi * W_ + pxi] = make_float4(r, g, bl, T);
}

__global__ __launch_bounds__(256)
void gr_combine(const float4* __restrict__ part, float* __restrict__ out) {
    int idx = blockIdx.x * 256 + threadIdx.x;     // [0, BATCH*NPIX)
    if (idx >= BATCH * NPIX) return;
    int b = idx / NPIX;
    int p = idx - b * NPIX;
    // res = o0 + T0*(o1 + T1*(... + T6*o7)), accumulated back-to-front
    float4 o = part[((NCHUNK-1) * BATCH + b) * NPIX + p];
    float r = o.x, gg = o.y, bb = o.z;
    #pragma unroll
    for (int i = NCHUNK-2; i >= 0; --i) {
        float4 oi = part[(i * BATCH + b) * NPIX + p];
        r  = fmaf(oi.w, r,  oi.x);
        gg = fmaf(oi.w, gg, oi.y);
        bb = fmaf(oi.w, bb, oi.z);
    }
    r  = fminf(fmaxf(r , 0.f), 1.f);
    gg = fminf(fmaxf(gg, 0.f), 1.f);
    bb = fminf(fmaxf(bb, 0.f), 1.f);
    out[(b * 3 + 0) * NPIX + p] = r;
    out[(b * 3 + 1) * NPIX + p] = gg;
    out[(b * 3 + 2) * NPIX + p] = bb;
}

extern "C" void kernel_launch(void* const* d_in, const int* in_sizes, int n_in,
                              void* d_out, int out_size, void* d_ws, size_t ws_size,
                              hipStream_t stream) {
    const float* means  = (const float*)d_in[0];
    const float* scales = (const float*)d_in[1];
    const float* rots   = (const float*)d_in[2];
    const float* colors = (const float*)d_in[3];
    const float* opac   = (const float*)d_in[4];
    float* out = (float*)d_out;

    int total = BATCH * NG;                       // 1536
    float4* cullA = (float4*)d_ws;                // 1536 * 16 B
    float4* pay   = cullA + total;                // 1536 * 32 B
    float4* part  = pay + 2 * total;              // 8*2*25600 * 16 B

    gr_precompute<<<(total + 255) / 256, 256, 0, stream>>>(
        means, scales, rots, colors, opac, cullA, pay, total);

    dim3 rgrid(NTILE, NCHUNK / 4, BATCH);         // (400, 2, 2) x 256 threads
    gr_render<<<rgrid, 256, 0, stream>>>(cullA, pay, part);

    gr_combine<<<(BATCH * NPIX + 255) / 256, 256, 0, stream>>>(part, out);
}

// Round 5
// 73.647 us; speedup vs baseline: 1.5756x; 1.0564x over previous
//
#include <hip/hip_runtime.h>
#include <hip/hip_fp16.h>
#include <string.h>

// Problem constants (match setup_inputs: B=2, N=768, H=W=160)
#define BATCH   2
#define NG      768
#define H_      160
#define W_      160
#define NPIX    (H_ * W_)          // 25600
#define NCHUNK  8
#define CHUNK   (NG / NCHUNK)      // 96
#define TILE    8
#define TPD     (W_ / TILE)        // 20 tiles per dim
#define NTILE   (TPD * TPD)        // 400
#define EPS2D_  0.3f
#define SZ2_    1.0e-6f            // 0.001^2
#define ALPHA_MAX_ 0.999f
#define KEXP    (-0.7213475204444817f)   // -0.5 * log2(e)
#define LN_CULL_EPS (-13.815511f)        // ln(1e-6): cull gaussians with max alpha < 1e-6

// cull[i]    = (mx, my, ex, ey)            : mean + axis-aligned influence extent
// pay[2i]    = (A, B, C, D)                : alpha = min(exp2(A x^2+B xy+C y^2+D x+E y+F), .999)
// pay[2i+1]  = (E, F, half2(cr,cg), cb)

__global__ __launch_bounds__(256)
void gr_precompute(const float* __restrict__ means,
                   const float* __restrict__ scales,
                   const float* __restrict__ rots,
                   const float* __restrict__ colors,
                   const float* __restrict__ opac,
                   float4* __restrict__ cull, float4* __restrict__ pay, int total) {
    int i = blockIdx.x * blockDim.x + threadIdx.x;
    if (i >= total) return;
    float theta = rots[i];
    float c = cosf(theta), s = sinf(theta);
    float sx = scales[2*i], sy = scales[2*i+1];
    float sx2 = sx*sx, sy2 = sy*sy;
    float a  = c*c*sx2 + s*s*sy2;
    float bb = c*s*(sx2 - sy2);
    float d  = s*s*sx2 + c*c*sy2;
    float mx = means[2*i], my = means[2*i+1];
    float cxx = a + SZ2_*mx*mx + EPS2D_;
    float cxy = bb + SZ2_*mx*my;
    float cyy = d + SZ2_*my*my + EPS2D_;
    float det = cxx*cyy - cxy*cxy;
    float inv = 1.0f / det;
    float ca  =  cyy * inv;
    float cb2 = -cxy * inv;
    float cc  =  cxx * inv;
    float op  = opac[i];

    // influence extent: alpha >= eps  =>  mahalanobis^2 <= 2*ln(op/eps)
    // marginal projection: |dx| <= k*sqrt(cov_xx), |dy| <= k*sqrt(cov_yy)
    float k2 = 2.0f * (logf(op) - LN_CULL_EPS);
    k2 = fmaxf(k2, 0.0f);
    float kk = sqrtf(k2);
    float ex = kk * sqrtf(cxx);
    float ey = kk * sqrtf(cyy);
    cull[i] = make_float4(mx, my, ex, ey);

    float A = KEXP * ca;
    float B = KEXP * 2.0f * cb2;
    float C = KEXP * cc;
    float D = KEXP * (-2.0f * ca * mx - 2.0f * cb2 * my);
    float E = KEXP * (-2.0f * cc * my - 2.0f * cb2 * mx);
    float F = KEXP * (ca*mx*mx + 2.0f*cb2*mx*my + cc*my*my) + log2f(op);
    float cr = colors[3*i], cg = colors[3*i+1], cb = colors[3*i+2];
    __half2 h2 = __floats2half2_rn(cr, cg);
    float rg; memcpy(&rg, &h2, 4);
    pay[2*i]   = make_float4(A, B, C, D);
    pay[2*i+1] = make_float4(E, F, rg, cb);
}

// Fused render+combine. Block = one 8x8 pixel tile x 4 waves.
// Wave w composites chunks 2w and 2w+1 (96 gaussians each) sequentially:
// box-cull -> order-preserving ballot compaction into this wave's LDS region
// (reused across both chunks) -> composite via broadcast ds_read.
// The two chunk results fold into one partial (r,g,b,T) per wave; after one
// __syncthreads, every wave combines the 4 partials back-to-front and waves
// 0..2 each write one color plane.
__global__ __launch_bounds__(256)
void gr_render(const float4* __restrict__ cull, const float4* __restrict__ pay,
               float* __restrict__ out) {
    __shared__ float4 stage[4][CHUNK * 2];   // per-wave survivor payloads
    __shared__ float4 partl[4][64];          // per-wave combined partial
    int tid  = threadIdx.x;
    int wave = tid >> 6;
    int lane = tid & 63;
    int tile = blockIdx.x;                   // [0, 400)
    int b    = blockIdx.y;
    int tx = tile % TPD, ty = tile / TPD;
    int pxi = tx * TILE + (lane & 7);
    int pyi = ty * TILE + (lane >> 3);
    float px = (float)pxi + 0.5f;
    float py = (float)pyi + 0.5f;
    float cxm = (float)(tx * TILE) + 0.5f * TILE;   // tile center
    float cym = (float)(ty * TILE) + 0.5f * TILE;
    const float RH = 0.5f * TILE;                   // tile half-extent (4)
    float x2 = px*px, xy = px*py, y2 = py*py;

    float R = 0.f, G = 0.f, B = 0.f, T = 1.f;       // wave's running composite

    #pragma unroll
    for (int cc = 0; cc < 2; ++cc) {
        int chunk = wave * 2 + cc;
        int base  = b * NG + chunk * CHUNK;
        int cnt = 0;

        {   // cull batch 0: gaussians [0, 64)
            float4 cu = cull[base + lane];
            bool keep = (fabsf(cu.x - cxm) <= cu.z + RH) &&
                        (fabsf(cu.y - cym) <= cu.w + RH);
            unsigned long long m = __ballot(keep);
            unsigned pre = __builtin_amdgcn_mbcnt_hi((unsigned)(m >> 32),
                            __builtin_amdgcn_mbcnt_lo((unsigned)m, 0u));
            if (keep) {
                int gi = base + lane;
                stage[wave][2*pre]     = pay[2*gi];
                stage[wave][2*pre + 1] = pay[2*gi + 1];
            }
            cnt = (int)__popcll(m);
        }
        {   // cull batch 1: gaussians [64, 96) — lanes 32..63 idle
            bool valid = lane < (CHUNK - 64);
            int gi = base + 64 + (valid ? lane : 0);   // clamped, in-bounds
            float4 cu = cull[gi];
            bool keep = valid &&
                        (fabsf(cu.x - cxm) <= cu.z + RH) &&
                        (fabsf(cu.y - cym) <= cu.w + RH);
            unsigned long long m = __ballot(keep);
            unsigned pre = __builtin_amdgcn_mbcnt_hi((unsigned)(m >> 32),
                            __builtin_amdgcn_mbcnt_lo((unsigned)m, 0u));
            if (keep) {
                int slot = cnt + (int)pre;
                stage[wave][2*slot]     = pay[2*gi];
                stage[wave][2*slot + 1] = pay[2*gi + 1];
            }
            cnt += (int)__popcll(m);
        }

        // composite survivors (broadcast ds_read, wave-uniform address)
        for (int i = 0; i < cnt; ++i) {
            float4 av = stage[wave][2*i];
            float4 ev = stage[wave][2*i + 1];
            float q = fmaf(av.x, x2,
                      fmaf(av.y, xy,
                      fmaf(av.z, y2,
                      fmaf(av.w, px,
                      fmaf(ev.x, py, ev.y)))));
            float al = fminf(__builtin_exp2f(q), ALPHA_MAX_);
            float w  = T * al;
            __half2 h2; memcpy(&h2, &ev.z, 4);
            float2 rg = __half22float2(h2);
            R  = fmaf(w, rg.x, R);
            G  = fmaf(w, rg.y, G);
            B  = fmaf(w, ev.w, B);
            T -= w;
            if (((i & 7) == 7) && __all(T < 1.0e-4f)) break;
        }
        if (__all(T < 1.0e-4f)) break;   // second chunk can't contribute
    }

    partl[wave][lane] = make_float4(R, G, B, T);
    __syncthreads();

    // every wave combines the 4 partials; waves 0..2 write plane = wave
    float4 o = partl[3][lane];
    float r = o.x, g = o.y, bb = o.z;
    #pragma unroll
    for (int i = 2; i >= 0; --i) {
        float4 oi = partl[i][lane];
        r  = fmaf(oi.w, r,  oi.x);
        g  = fmaf(oi.w, g,  oi.y);
        bb = fmaf(oi.w, bb, oi.z);
    }
    if (wave < 3) {
        float v = (wave == 0) ? r : (wave == 1) ? g : bb;
        v = fminf(fmaxf(v, 0.f), 1.f);
        out[(b * 3 + wave) * NPIX + pyi * W_ + pxi] = v;
    }
}

extern "C" void kernel_launch(void* const* d_in, const int* in_sizes, int n_in,
                              void* d_out, int out_size, void* d_ws, size_t ws_size,
                              hipStream_t stream) {
    const float* means  = (const float*)d_in[0];
    const float* scales = (const float*)d_in[1];
    const float* rots   = (const float*)d_in[2];
    const float* colors = (const float*)d_in[3];
    const float* opac   = (const float*)d_in[4];
    float* out = (float*)d_out;

    int total = BATCH * NG;                       // 1536
    float4* cullA = (float4*)d_ws;                // 1536 * 16 B
    float4* pay   = cullA + total;                // 1536 * 32 B

    gr_precompute<<<(total + 255) / 256, 256, 0, stream>>>(
        means, scales, rots, colors, opac, cullA, pay, total);

    dim3 rgrid(NTILE, BATCH);                     // (400, 2) x 256 threads
    gr_render<<<rgrid, 256, 0, stream>>>(cullA, pay, out);
}